// Round 4
// baseline (225.206 us; speedup 1.0000x reference)
//
#include <hip/hip_runtime.h>

// RoPE: X (L=2048, D=4096, N=4) fp32 -> out same shape.
// Round 7 (4th in session). Model from rounds 0-3: dur_us = ~161us of 512MiB
// poison fills (2x ~80us, always the top dispatches) + kernel. Kernel is
// <78.8us (never in top-5) and ~50-57us by subtraction => ~5 TB/s, vs 42.6us
// floor at copy-rate 6.3 TB/s. Math is fully hidden; remaining lever is
// streaming efficiency.
// This round: drop nontemporal from LOADS only. X is static across timed
// iterations (only output/ws are poisoned), so input can partially persist in
// the 256MiB L3 -- but nt-loads bypass L3 and force every read to HBM.
// Normal loads let the read side hit L3, freeing HBM for the write stream.
// Stores stay nt (output is re-poisoned every iteration; don't pollute L3).
// Numerics unchanged from passing rounds: per-thread correctly-rounded double
// pow theta, ang = fl32((l+1)*theta), fp64 mod-2pi reduction (~1e-9 rad),
// small-arg sincosf. absmax must stay 0.03125.

#define L_DIM 2048
#define D_DIM 4096   // vec4 elements per row (N=4 folded into one vec4)
#define HALF 2048
#define NTHREADS 256
#define NBLOCKS 8192
// threads = 2,097,152 = L*HALF/2; each thread does rows lA and lA+1024

typedef float floatx4 __attribute__((ext_vector_type(4)));

__device__ __forceinline__ void rot_pair(float ang, floatx4 x1, floatx4 x2,
                                         floatx4& o1, floatx4& o2) {
    // fp64 reduction mod 2*pi: ang exact as double, q <= ~3.4e6,
    // hi/lo split of 2*pi -> |err| ~1e-9 rad; then small-arg sincosf.
    double ad = (double)ang;
    double q  = rint(ad * 1.5915494309189534e-1);       // 1/(2*pi)
    double r  = fma(-q, 6.283185307179586, ad);          // 2*pi hi
    r         = fma(-q, 2.4492935982947064e-16, r);      // 2*pi lo
    float rf  = (float)r;

    float s, c;
    sincosf(rf, &s, &c);

    o1 = c * x1 - s * x2;
    o2 = s * x1 + c * x2;
}

__global__ __launch_bounds__(256) void rope_kernel(const floatx4* __restrict__ X,
                                                   floatx4* __restrict__ out) {
    int tid = blockIdx.x * NTHREADS + threadIdx.x;   // 0 .. 2097151
    int j  = tid & (HALF - 1);    // fixed per thread
    int lA = tid >> 11;           // 0 .. 1023
    int lB = lA + 1024;

    int bA = lA * D_DIM + j;      // vec4 index of x1, row A
    int bB = lB * D_DIM + j;      // row B

    // Plain (cache-allocating) loads: X is iteration-static, let L3 serve it.
    floatx4 x1a = X[bA];
    floatx4 x2a = X[bA + HALF];
    floatx4 x1b = X[bB];
    floatx4 x2b = X[bB + HALF];

    // theta once per thread: correctly-rounded f32 of 10000^(j/2048),
    // same expression as the passing kernels (absmax anchor).
    double e = (double)j * (1.0 / 2048.0);
    float theta = (float)pow(10000.0, e);

    float angA = (float)(lA + 1) * theta;   // single f32 multiply, as reference
    float angB = (float)(lB + 1) * theta;

    floatx4 o1a, o2a, o1b, o2b;
    rot_pair(angA, x1a, x2a, o1a, o2a);
    rot_pair(angB, x1b, x2b, o1b, o2b);

    // Stores stay nontemporal: output is re-poisoned before next iteration.
    __builtin_nontemporal_store(o1a, &out[bA]);
    __builtin_nontemporal_store(o2a, &out[bA + HALF]);
    __builtin_nontemporal_store(o1b, &out[bB]);
    __builtin_nontemporal_store(o2b, &out[bB + HALF]);
}

extern "C" void kernel_launch(void* const* d_in, const int* in_sizes, int n_in,
                              void* d_out, int out_size, void* d_ws, size_t ws_size,
                              hipStream_t stream) {
    const floatx4* X = (const floatx4*)d_in[0];
    floatx4* out = (floatx4*)d_out;
    rope_kernel<<<dim3(NBLOCKS), dim3(NTHREADS), 0, stream>>>(X, out);
}

// Round 5
// 219.888 us; speedup vs baseline: 1.0242x; 1.0242x over previous
//
#include <hip/hip_runtime.h>

// RoPE: X (L=2048, D=4096, N=4) fp32 -> out same shape.
// Round 8 (5th in session) -- FINAL: revert to the best-measured variant
// (round-3 kernel, dur_us 218.4): nontemporal loads AND stores, 2 rows/thread,
// 8192 blocks. Round-4's plain-load (L3-retention) theory is dead: 225.2us --
// the 512MiB harness poison fills wipe L3 between iterations, so allocating X
// in cache costs allocation traffic and buys nothing.
// Session model (rocprof-backed): dur_us = ~161us fixed harness fills (2x
// ~80us 512MiB fillBuffer, always the top dispatches; rope_kernel never
// appears => <78.8us) + kernel ~57us = ~4.7-5 TB/s mixed RW stream, i.e. the
// practical read+write plateau (write-only fill rate is 6.7 TB/s; 42.6us
// would be the pure copy-rate floor). Math (theta via per-thread double pow,
// fp64 mod-2pi reduction, small-arg sincosf) costs ~3us total, fully hidden.
// Numerics: theta = correctly-rounded f32 of 10000^(j/2048); ang =
// fl32((l+1)*theta); reduction err ~1e-9 rad. absmax 0.03125 (= accepted).

#define L_DIM 2048
#define D_DIM 4096   // vec4 elements per row (N=4 folded into one vec4)
#define HALF 2048
#define NTHREADS 256
#define NBLOCKS 8192
// threads = 2,097,152 = L*HALF/2; each thread does rows lA and lA+1024

typedef float floatx4 __attribute__((ext_vector_type(4)));

__device__ __forceinline__ void rot_pair(float ang, floatx4 x1, floatx4 x2,
                                         floatx4& o1, floatx4& o2) {
    // fp64 reduction mod 2*pi: ang exact as double, q <= ~3.4e6,
    // hi/lo split of 2*pi -> |err| ~1e-9 rad; then small-arg sincosf.
    double ad = (double)ang;
    double q  = rint(ad * 1.5915494309189534e-1);       // 1/(2*pi)
    double r  = fma(-q, 6.283185307179586, ad);          // 2*pi hi
    r         = fma(-q, 2.4492935982947064e-16, r);      // 2*pi lo
    float rf  = (float)r;

    float s, c;
    sincosf(rf, &s, &c);

    o1 = c * x1 - s * x2;
    o2 = s * x1 + c * x2;
}

__global__ __launch_bounds__(256) void rope_kernel(const floatx4* __restrict__ X,
                                                   floatx4* __restrict__ out) {
    int tid = blockIdx.x * NTHREADS + threadIdx.x;   // 0 .. 2097151
    int j  = tid & (HALF - 1);    // fixed per thread
    int lA = tid >> 11;           // 0 .. 1023
    int lB = lA + 1024;

    int bA = lA * D_DIM + j;      // vec4 index of x1, row A
    int bB = lB * D_DIM + j;      // row B

    // Issue all 4 stream loads before any math (nontemporal: one-touch data).
    floatx4 x1a = __builtin_nontemporal_load(&X[bA]);
    floatx4 x2a = __builtin_nontemporal_load(&X[bA + HALF]);
    floatx4 x1b = __builtin_nontemporal_load(&X[bB]);
    floatx4 x2b = __builtin_nontemporal_load(&X[bB + HALF]);

    // theta once per thread: correctly-rounded f32 of 10000^(j/2048),
    // same expression as all passing kernels (absmax anchor).
    double e = (double)j * (1.0 / 2048.0);
    float theta = (float)pow(10000.0, e);

    float angA = (float)(lA + 1) * theta;   // single f32 multiply, as reference
    float angB = (float)(lB + 1) * theta;

    floatx4 o1a, o2a, o1b, o2b;
    rot_pair(angA, x1a, x2a, o1a, o2a);
    rot_pair(angB, x1b, x2b, o1b, o2b);

    __builtin_nontemporal_store(o1a, &out[bA]);
    __builtin_nontemporal_store(o2a, &out[bA + HALF]);
    __builtin_nontemporal_store(o1b, &out[bB]);
    __builtin_nontemporal_store(o2b, &out[bB + HALF]);
}

extern "C" void kernel_launch(void* const* d_in, const int* in_sizes, int n_in,
                              void* d_out, int out_size, void* d_ws, size_t ws_size,
                              hipStream_t stream) {
    const floatx4* X = (const floatx4*)d_in[0];
    floatx4* out = (floatx4*)d_out;
    rope_kernel<<<dim3(NBLOCKS), dim3(NTHREADS), 0, stream>>>(X, out);
}